// Round 6
// baseline (376.514 us; speedup 1.0000x reference)
//
#include <hip/hip_runtime.h>

#define N_NODES 50000
#define N_EDGES 1600000
#define NPB     16
#define NB      196    // node buckets, W=256 nodes each (r>>8)
#define TILE    1024   // records per LDS staging tile
#define RSTR    12     // floats per record (id + 9 frames + 2 pad) = 48B, 16B-aligned
#define MSTR    164
#define EPSV    1e-8f

typedef float f32x4 __attribute__((ext_vector_type(4)));
typedef short s16x8 __attribute__((ext_vector_type(8)));

__device__ __forceinline__ float sigmoidf_(float x) { return 1.0f / (1.0f + __expf(-x)); }
__device__ __forceinline__ short f2bf(float x) {
    unsigned u = __float_as_uint(x);
    unsigned r = (u + 0x7FFFu + ((u >> 16) & 1u)) >> 16;
    return (short)r;
}
__device__ __forceinline__ float bf2f(short h) {
    return __uint_as_float(((unsigned)(unsigned short)h) << 16);
}

__global__ __launch_bounds__(256) void prep_w_kernel(
    const float* __restrict__ W_so, short* __restrict__ Whi, short* __restrict__ Wlo) {
    int i = blockIdx.x * 256 + threadIdx.x;
    if (i >= 160 * 128) return;
    int k = i >> 7;
    float w = (k < 153) ? W_so[i] : 0.0f;
    short hh = f2bf(w);
    Whi[i] = hh;
    Wlo[i] = f2bf(w - bf2f(hh));
}

// ---------------------------------------------------------------------------
// Pass A: counting-sort partition of edges into 196 node-range buckets.
// Round-5 counters: node gather was 205 MB of random reads at 1.5 TB/s.
// Here frame data moves ONCE, coalesced: block counts its edges (LDS),
// reserves runs with 196 global atomics/block, tile-sorts in LDS, writes
// bucket-grouped 48B records streaming. Overflow -> Fovf atomics (never).
// ---------------------------------------------------------------------------
__global__ __launch_bounds__(256) void partition_kernel(
    const int* __restrict__ row,
    const float* __restrict__ frames,
    int chunk_base, int chunk_end, int tiles_per_block,
    int* __restrict__ gcnt,
    float* __restrict__ recs, int capb,
    float* __restrict__ Fovf)
{
    __shared__ int cntB[NB];
    __shared__ int gb[NB];
    __shared__ int woff[NB];
    __shared__ int cntT[NB];
    __shared__ int curT[NB];
    __shared__ int pfx[256];
    __shared__ __align__(16) float stage[TILE * RSTR];  // 48 KB

    const int t = threadIdx.x;
    const int bb = chunk_base + blockIdx.x * tiles_per_block * TILE;

    // block-level count (for one reservation per block)
    if (t < NB) cntB[t] = 0;
    __syncthreads();
    for (int j = 0; j < 4 * tiles_per_block; j++) {
        int e = bb + t + j * 256;
        if (e < chunk_end) atomicAdd(&cntB[row[e] >> 8], 1);
    }
    __syncthreads();
    if (t < NB) { gb[t] = atomicAdd(&gcnt[t], cntB[t]); woff[t] = 0; }
    __syncthreads();

    for (int ti = 0; ti < tiles_per_block; ti++) {
        int tbase = bb + ti * TILE;
        if (tbase >= chunk_end) break;
        int tile_cnt = chunk_end - tbase; if (tile_cnt > TILE) tile_cnt = TILE;

        if (t < NB) { cntT[t] = 0; curT[t] = 0; }
        __syncthreads();

        int rr[4], bkt[4];
#pragma unroll
        for (int i = 0; i < 4; i++) {
            int e = tbase + t + i * 256;
            if (e < chunk_end) {
                rr[i] = row[e]; bkt[i] = rr[i] >> 8;
                atomicAdd(&cntT[bkt[i]], 1);
            } else bkt[i] = -1;
        }
        __syncthreads();
        // inclusive Hillis-Steele scan over padded 256
        int c0 = (t < NB) ? cntT[t] : 0;
        pfx[t] = c0;
        __syncthreads();
        for (int off = 1; off < 256; off <<= 1) {
            int vv = (t >= off) ? pfx[t - off] : 0;
            __syncthreads();
            pfx[t] += vv;
            __syncthreads();
        }
        // place into stage, sorted by bucket
#pragma unroll
        for (int i = 0; i < 4; i++) {
            if (bkt[i] >= 0) {
                int b = bkt[i];
                int rank = atomicAdd(&curT[b], 1);
                int slot = pfx[b] - cntT[b] + rank;
                int e = tbase + t + i * 256;
                const float* fp = frames + (size_t)e * 9;
                float4 w0; w0.x = __int_as_float(rr[i]); w0.y = fp[0]; w0.z = fp[1]; w0.w = fp[2];
                float4 w1 = {fp[3], fp[4], fp[5], fp[6]};
                *(float4*)&stage[slot * RSTR] = w0;
                *(float4*)&stage[slot * RSTR + 4] = w1;
                stage[slot * RSTR + 8] = fp[7];
                stage[slot * RSTR + 9] = fp[8];
            }
        }
        __syncthreads();
        // copy out: consecutive slots in a bucket -> consecutive global records
        for (int s = t; s < tile_cnt; s += 256) {
            float4 a0 = *(float4*)&stage[s * RSTR];
            float4 a1 = *(float4*)&stage[s * RSTR + 4];
            float f7 = stage[s * RSTR + 8], f8 = stage[s * RSTR + 9];
            int id = __float_as_int(a0.x);
            int b = id >> 8;
            int dib = gb[b] + woff[b] + (s - (pfx[b] - cntT[b]));
            if (dib < capb) {
                float* dp = recs + ((size_t)b * capb + dib) * RSTR;
                *(float4*)dp = a0;
                *(float4*)(dp + 4) = a1;
                dp[8] = f7; dp[9] = f8;
            } else {
                float vals[9] = {a0.y, a0.z, a0.w, a1.x, a1.y, a1.z, a1.w, f7, f8};
#pragma unroll
                for (int k = 0; k < 9; k++) atomicAdd(&Fovf[(size_t)id * 10 + k], vals[k]);
                atomicAdd(&Fovf[(size_t)id * 10 + 9], 1.0f);
            }
        }
        __syncthreads();
        if (t < NB) woff[t] += cntT[t];
        __syncthreads();
    }
}

// ---------------------------------------------------------------------------
// Pass B: one block per bucket streams its records (coalesced) and reduces
// into LDS (256 nodes x 10), then adds into Fsum (exclusive node ranges;
// chunks are sequential dispatches -> plain RMW is race-free).
// ---------------------------------------------------------------------------
__global__ __launch_bounds__(256) void accum_kernel(
    const float* __restrict__ recs, const int* __restrict__ gcnt, int capb,
    float* __restrict__ Fsum)
{
    __shared__ float acc[256 * 10];
    const int b = blockIdx.x, t = threadIdx.x;
    for (int i = t; i < 2560; i += 256) acc[i] = 0.f;
    __syncthreads();
    int cntb = gcnt[b]; if (cntb > capb) cntb = capb;
    for (int j = t; j < cntb; j += 256) {
        const float* rp = recs + ((size_t)b * capb + j) * RSTR;
        float4 a0 = *(const float4*)rp;
        float4 a1 = *(const float4*)(rp + 4);
        float f7 = rp[8], f8 = rp[9];
        int nl = __float_as_int(a0.x) & 255;
        float* ap = &acc[nl * 10];
        atomicAdd(ap + 0, a0.y); atomicAdd(ap + 1, a0.z); atomicAdd(ap + 2, a0.w);
        atomicAdd(ap + 3, a1.x); atomicAdd(ap + 4, a1.y); atomicAdd(ap + 5, a1.z);
        atomicAdd(ap + 6, a1.w); atomicAdd(ap + 7, f7);   atomicAdd(ap + 8, f8);
        atomicAdd(ap + 9, 1.0f);
    }
    __syncthreads();
    for (int i = t; i < 2560; i += 256) {
        int nl = i / 10, k = i % 10;
        int n = (b << 8) + nl;
        if (n < N_NODES) Fsum[(size_t)n * 16 + k] += acc[i];
    }
}

// ---------------------------------------------------------------------------
// Kernel 3: per-node algebra, 16 nodes/block. Frame sums read directly.
// ---------------------------------------------------------------------------
__global__ __launch_bounds__(256) void node_kernel(
    const float* __restrict__ s,
    const float* __restrict__ v,
    const float* __restrict__ W_vd,
    const float* __restrict__ W_vdf,
    const short* __restrict__ Whi,
    const short* __restrict__ Wlo,
    const float* __restrict__ b_so,
    const float* __restrict__ W_vu,
    const float* __restrict__ W_vosf,
    const float* __restrict__ b_vosf,
    const float* __restrict__ W_vuf,
    const float* __restrict__ Fsum,
    const float* __restrict__ Fovf,
    float* __restrict__ out0,
    float* __restrict__ out1)
{
    __shared__ float vL[NPB][48];
    __shared__ float vhL[NPB][3][16];
    __shared__ __align__(16) float mergedL[NPB][MSTR];
    __shared__ float redL[NPB][16][9];
    __shared__ float tmpL[NPB][10];
    __shared__ float FbarL[NPB][9];
    __shared__ float vdfL[NPB][9];
    __shared__ __align__(16) float sigL[NPB][128];
    __shared__ float gateL[NPB][12];

    const int t = threadIdx.x;
    const int base = blockIdx.x * NPB;
    const int nn = t >> 4, h = t & 15;
    const int n = base + nn;

    // ---- phase 0: stage v, s; read frame sums ----
#pragma unroll
    for (int r = 0; r < 3; r++) vL[nn][h * 3 + r] = v[(size_t)n * 48 + h * 3 + r];
#pragma unroll
    for (int r = 0; r < 8; r++) mergedL[nn][h * 8 + r] = s[(size_t)n * 128 + h * 8 + r];
    if (h < 10) tmpL[nn][h] = Fsum[(size_t)n * 16 + h] + Fovf[(size_t)n * 10 + h];
    __syncthreads();

    // ---- phase 1b: vh, vnorm, Fbar, vdf ----
    {
        float vh0 = 0.f, vh1 = 0.f, vh2 = 0.f;
#pragma unroll
        for (int i = 0; i < 16; i++) {
            float w = W_vd[i * 16 + h];
            vh0 += vL[nn][i * 3 + 0] * w;
            vh1 += vL[nn][i * 3 + 1] * w;
            vh2 += vL[nn][i * 3 + 2] * w;
        }
        vhL[nn][0][h] = vh0; vhL[nn][1][h] = vh1; vhL[nn][2][h] = vh2;
        mergedL[nn][128 + h] = sqrtf(vh0 * vh0 + vh1 * vh1 + vh2 * vh2 + EPSV);
        if (h < 9) {
            float inv = 1.0f / fmaxf(tmpL[nn][9], 1.0f);
            FbarL[nn][h] = tmpL[nn][h] * inv;
        }
        if (h < 3) {
            int cc = h;
#pragma unroll
            for (int j = 0; j < 3; j++) {
                float a = 0.f;
#pragma unroll
                for (int i = 0; i < 16; i++) a += vL[nn][i * 3 + j] * W_vdf[i * 3 + cc];
                vdfL[nn][j * 3 + cc] = a;
            }
        }
    }
    __syncthreads();

    // ---- phase 1c: sh + zero-pad merged[144..163] ----
    {
        if (h < 9) {
            int c = h / 3, i = h % 3;
            float a = 0.f;
#pragma unroll
            for (int j = 0; j < 3; j++) a += FbarL[nn][i * 3 + j] * vdfL[nn][j * 3 + c];
            mergedL[nn][144 + h] = a;
        } else {
            mergedL[nn][144 + h] = 0.0f;
        }
        if (h < 4) mergedL[nn][160 + h] = 0.0f;
    }
    __syncthreads();

    // ---- phase 2: C[16x128] = merged[16x160] @ W_so via split-bf16 MFMA ----
    {
        const int w = t >> 6;
        const int lane = t & 63;
        const int quad = lane >> 4;
        const int col = lane & 15;
        f32x4 acc[2];
        acc[0] = (f32x4){0.f, 0.f, 0.f, 0.f};
        acc[1] = (f32x4){0.f, 0.f, 0.f, 0.f};
#pragma unroll
        for (int kk = 0; kk < 5; kk++) {
            const int krow = kk * 32 + quad * 8;
            const float* ap = &mergedL[col][krow];
            float4 a0v = *(const float4*)ap;
            float4 a1v = *(const float4*)(ap + 4);
            float av[8] = {a0v.x, a0v.y, a0v.z, a0v.w, a1v.x, a1v.y, a1v.z, a1v.w};
            s16x8 ahi, alo;
#pragma unroll
            for (int j = 0; j < 8; j++) {
                short hh = f2bf(av[j]);
                ahi[j] = hh;
                alo[j] = f2bf(av[j] - bf2f(hh));
            }
#pragma unroll
            for (int t0 = 0; t0 < 2; t0++) {
                int o = w * 32 + t0 * 16 + col;
                s16x8 bhi, blo;
#pragma unroll
                for (int j = 0; j < 8; j++) {
                    bhi[j] = Whi[(krow + j) * 128 + o];
                    blo[j] = Wlo[(krow + j) * 128 + o];
                }
                acc[t0] = __builtin_amdgcn_mfma_f32_16x16x32_bf16(ahi, bhi, acc[t0], 0, 0, 0);
                acc[t0] = __builtin_amdgcn_mfma_f32_16x16x32_bf16(ahi, blo, acc[t0], 0, 0, 0);
                acc[t0] = __builtin_amdgcn_mfma_f32_16x16x32_bf16(alo, bhi, acc[t0], 0, 0, 0);
            }
        }
#pragma unroll
        for (int t0 = 0; t0 < 2; t0++) {
            int o = w * 32 + t0 * 16 + col;
            float bso = b_so[o];
#pragma unroll
            for (int r = 0; r < 4; r++) {
                int nl = quad * 4 + r;
                float val = acc[t0][r] + bso;
                out0[(size_t)(base + nl) * 128 + o] = fmaxf(val, 0.0f);
                sigL[nl][o] = sigmoidf_(val);
            }
        }
    }
    __syncthreads();

    // ---- gate = sigmoid(sr) @ W_vosf + b_vosf ----
    {
        const float* sp = &sigL[nn][h * 8];
        float4 s0 = *(const float4*)sp;
        float4 s1 = *(const float4*)(sp + 4);
        float sv[8] = {s0.x, s0.y, s0.z, s0.w, s1.x, s1.y, s1.z, s1.w};
        float p[9];
#pragma unroll
        for (int k = 0; k < 9; k++) p[k] = 0.f;
#pragma unroll
        for (int i = 0; i < 8; i++) {
            int o = h * 8 + i;
#pragma unroll
            for (int k = 0; k < 9; k++) p[k] += sv[i] * W_vosf[o * 9 + k];
        }
#pragma unroll
        for (int k = 0; k < 9; k++) redL[nn][h][k] = p[k];
    }
    __syncthreads();
    if (h < 9) {
        float a = b_vosf[h];
#pragma unroll
        for (int j = 0; j < 16; j++) a += redL[nn][j][h];
        gateL[nn][h] = a;
    }
    __syncthreads();

    // ---- phase 3: vector path ----
    {
        int o = h;
        float gv[9];
#pragma unroll
        for (int i = 0; i < 3; i++)
#pragma unroll
            for (int kk = 0; kk < 3; kk++) {
                float a = 0.f;
#pragma unroll
                for (int j = 0; j < 3; j++) a += gateL[nn][j * 3 + i] * FbarL[nn][j * 3 + kk];
                gv[i * 3 + kk] = a;
            }
        float gvr[3];
#pragma unroll
        for (int kk = 0; kk < 3; kk++) {
            float a = 0.f;
#pragma unroll
            for (int i = 0; i < 3; i++) a += gv[i * 3 + kk] * W_vuf[i * 16 + o];
            gvr[kk] = a;
        }
        float gn2 = sqrtf(gvr[0] * gvr[0] + gvr[1] * gvr[1] + gvr[2] * gvr[2] + EPSV);
        float sg = sigmoidf_(gn2);
#pragma unroll
        for (int c = 0; c < 3; c++) {
            float a = 0.f;
#pragma unroll
            for (int h2 = 0; h2 < 16; h2++) a += vhL[nn][c][h2] * W_vu[h2 * 16 + o];
            out1[(size_t)n * 48 + o * 3 + c] = a * sg;
        }
    }
}

static inline size_t align256(size_t x) { return (x + 255) & ~(size_t)255; }

extern "C" void kernel_launch(void* const* d_in, const int* in_sizes, int n_in,
                              void* d_out, int out_size, void* d_ws, size_t ws_size,
                              hipStream_t stream) {
    const float* s      = (const float*)d_in[0];
    const float* v      = (const float*)d_in[1];
    const float* frames = (const float*)d_in[2];
    const float* W_vd   = (const float*)d_in[3];
    const float* W_vdf  = (const float*)d_in[4];
    const float* W_so   = (const float*)d_in[5];
    const float* b_so   = (const float*)d_in[6];
    const float* W_vu   = (const float*)d_in[7];
    const float* W_vosf = (const float*)d_in[8];
    const float* b_vosf = (const float*)d_in[9];
    const float* W_vuf  = (const float*)d_in[10];
    const int* edge_index = (const int*)d_in[11];
    // d_in[12] = node_inputs (assumed truthy)

    // ws-adaptive chunking: records buffer = NB * capb * 48 B must fit.
    const size_t whi_b  = align256(160 * 128 * sizeof(short));
    const size_t fsum_b = align256((size_t)50016 * 16 * sizeof(float));
    const size_t fovf_b = align256((size_t)50016 * 10 * sizeof(float));
    int nchunks = 64, capb = 0, chunkE = 0;
    for (int k = 1; k <= 64; k++) {
        int ce = (N_EDGES + k - 1) / k;
        int cb = (int)((long long)ce * 13 / 10 / NB) + 256;
        size_t gcnt_b = align256((size_t)k * NB * sizeof(int));
        size_t recs_b = (size_t)NB * cb * RSTR * sizeof(float);
        if (gcnt_b + fsum_b + fovf_b + 2 * whi_b + recs_b <= ws_size) {
            nchunks = k; capb = cb; chunkE = ce; break;
        }
        if (k == 64) { nchunks = k; capb = cb; chunkE = ce; }  // best effort; Fovf covers overflow
    }
    const size_t gcnt_b = align256((size_t)nchunks * NB * sizeof(int));

    char* p = (char*)d_ws;
    int*   gcnt = (int*)p;             p += gcnt_b;
    float* Fsum = (float*)p;           p += fsum_b;
    float* Fovf = (float*)p;           p += fovf_b;
    short* Whi  = (short*)p;           p += whi_b;
    short* Wlo  = (short*)p;           p += whi_b;
    float* recs = (float*)p;
    float* out0 = (float*)d_out;
    float* out1 = out0 + (size_t)N_NODES * 128;

    hipMemsetAsync(d_ws, 0, gcnt_b + fsum_b + fovf_b, stream);
    prep_w_kernel<<<80, 256, 0, stream>>>(W_so, Whi, Wlo);

    for (int c = 0; c < nchunks; c++) {
        int cb_ = c * chunkE;
        int ce_ = cb_ + chunkE; if (ce_ > N_EDGES) ce_ = N_EDGES;
        int ecnt = ce_ - cb_;
        if (ecnt <= 0) break;
        int tpb = (ecnt + NB * TILE - 1) / (NB * TILE);   // tiles per block
        int epb = tpb * TILE;
        int nblk = (ecnt + epb - 1) / epb;
        partition_kernel<<<nblk, 256, 0, stream>>>(
            edge_index, frames, cb_, ce_, tpb, gcnt + c * NB, recs, capb, Fovf);
        accum_kernel<<<NB, 256, 0, stream>>>(recs, gcnt + c * NB, capb, Fsum);
    }

    node_kernel<<<N_NODES / NPB, 256, 0, stream>>>(
        s, v, W_vd, W_vdf, Whi, Wlo, b_so, W_vu, W_vosf, b_vosf, W_vuf,
        Fsum, Fovf, out0, out1);
}